// Round 1
// baseline (8576.675 us; speedup 1.0000x reference)
//
#include <hip/hip_runtime.h>
#include <stdint.h>
#include <math.h>

#define DM   128
#define NH   8
#define EHD  16
#define NLAY 5
#define DFF  64
#define NREP 128
#define NB   8
#define SL   4096
#define NC   27
#define NBH  (NB*NH)      // 64
#define NROWS (NB*SL)     // 32768

// ---------------- threefry2x32 (JAX-exact) ----------------
__device__ __forceinline__ uint32_t rotl32(uint32_t v, int d) {
  return (v << d) | (v >> (32 - d));
}

__device__ __forceinline__ void tf2x32(uint32_t k0, uint32_t k1,
                                       uint32_t x0, uint32_t x1,
                                       uint32_t &o0, uint32_t &o1) {
  uint32_t ks2 = k0 ^ k1 ^ 0x1BD11BDAu;
  x0 += k0; x1 += k1;
#define TFR(r) { x0 += x1; x1 = rotl32(x1, (r)); x1 ^= x0; }
  TFR(13) TFR(15) TFR(26) TFR(6)
  x0 += k1; x1 += ks2 + 1u;
  TFR(17) TFR(29) TFR(16) TFR(24)
  x0 += ks2; x1 += k0 + 2u;
  TFR(13) TFR(15) TFR(26) TFR(6)
  x0 += k0; x1 += k1 + 3u;
  TFR(17) TFR(29) TFR(16) TFR(24)
  x0 += k1; x1 += ks2 + 4u;
  TFR(13) TFR(15) TFR(26) TFR(6)
  x0 += ks2; x1 += k0 + 5u;
#undef TFR
  o0 = x0; o1 = x1;
}

// Partitionable-threefry randint bits for layer `layer`:
// key_l = tf(key42,(0,l)); split foldlike -> k2 = tf(key_l,(0,1));
// bits[i] = y0^y1 of tf(k2,(0,i));  idx = bits & 4095
__global__ void gen_bits_kernel(uint32_t* __restrict__ bits, int layer) {
  int i = blockIdx.x * blockDim.x + threadIdx.x;
  if (i >= SL * NC) return;
  uint32_t ka, kb, k2a, k2b, y0, y1;
  tf2x32(0u, 42u, 0u, (uint32_t)layer, ka, kb);   // fold_in
  tf2x32(ka, kb, 0u, 1u, k2a, k2b);               // split -> k2 (counter 1)
  tf2x32(k2a, k2b, 0u, (uint32_t)i, y0, y1);      // counter-mode bits
  bits[i] = y0 ^ y1;
}

// ---------------- layout transforms ----------------
// x[b, d, l] -> h[b, l, d]
__global__ void transpose_x_kernel(const float* __restrict__ x, float* __restrict__ h) {
  int idx = blockIdx.x * blockDim.x + threadIdx.x;
  if (idx >= NB * SL * DM) return;
  int d = idx & (DM - 1);
  int l = (idx >> 7) & (SL - 1);
  int b = idx >> 19;
  h[idx] = x[(b * DM + d) * SL + l];
}

// ---------------- QKV projection ----------------
// q/k/v layout: [b, h, l, e]  -> ((b*NH+h)*SL + l)*EHD + e
__global__ void qkv_kernel(const float* __restrict__ h,
                           const float* __restrict__ Wq, const float* __restrict__ bq,
                           const float* __restrict__ Wk, const float* __restrict__ bk,
                           const float* __restrict__ Wv, const float* __restrict__ bv,
                           float* __restrict__ q, float* __restrict__ k, float* __restrict__ v,
                           int layer) {
  int row = blockIdx.x;        // b*SL + l
  int d   = threadIdx.x;       // 0..127
  __shared__ float hs[DM];
  hs[d] = h[row * DM + d];
  __syncthreads();
  const float* wq = Wq + (layer * DM + d) * DM;
  const float* wk = Wk + (layer * DM + d) * DM;
  const float* wv = Wv + (layer * DM + d) * DM;
  float aq = bq[layer * DM + d];
  float ak = bk[layer * DM + d];
  float av = bv[layer * DM + d];
  for (int i = 0; i < DM; ++i) {
    float hv = hs[i];
    aq += hv * wq[i];
    ak += hv * wk[i];
    av += hv * wv[i];
  }
  int b = row >> 12, l = row & (SL - 1);
  int hh = d >> 4, e = d & 15;
  int o = ((b * NH + hh) * SL + l) * EHD + e;
  q[o] = aq; k[o] = ak; v[o] = av;
}

// ---------------- sampled scores -> M ----------------
__global__ void sampM_kernel(const float* __restrict__ q, const float* __restrict__ k,
                             const uint32_t* __restrict__ bits, float* __restrict__ M) {
  int t = blockIdx.x * blockDim.x + threadIdx.x;   // bh*SL + l (l fastest)
  if (t >= NBH * SL) return;
  int l  = t & (SL - 1);
  int bh = t >> 12;
  const float* qrow = q + (bh * SL + l) * EHD;
  float qv[EHD];
#pragma unroll
  for (int e = 0; e < EHD; ++e) qv[e] = qrow[e];
  float mx = -INFINITY, sm = 0.f;
  for (int u = 0; u < NC; ++u) {
    int ki = (int)(bits[l * NC + u] & (SL - 1));
    const float* krow = k + (bh * SL + ki) * EHD;
    float s = 0.f;
#pragma unroll
    for (int e = 0; e < EHD; ++e) s += qv[e] * krow[e];
    mx = fmaxf(mx, s);
    sm += s;
  }
  M[t] = mx - sm * (1.0f / (float)SL);
}

// ---------------- top-k (iterative argmax, stable ties) ----------------
__global__ void topk_kernel(const float* __restrict__ M, int* __restrict__ top) {
  int bh  = blockIdx.x;
  int tid = threadIdx.x;   // 256
  __shared__ float vals[SL];
  __shared__ float rmax[256];
  __shared__ int   ridx[256];
  for (int i = tid; i < SL; i += 256) vals[i] = M[bh * SL + i];
  __syncthreads();
  for (int u = 0; u < NC; ++u) {
    float bm = -INFINITY; int bi = SL;
    for (int i = tid; i < SL; i += 256) {
      float vv = vals[i];
      if (vv > bm) { bm = vv; bi = i; }
    }
    rmax[tid] = bm; ridx[tid] = bi;
    __syncthreads();
    for (int s = 128; s > 0; s >>= 1) {
      if (tid < s) {
        float v2 = rmax[tid + s]; int i2 = ridx[tid + s];
        if (v2 > rmax[tid] || (v2 == rmax[tid] && i2 < ridx[tid])) {
          rmax[tid] = v2; ridx[tid] = i2;
        }
      }
      __syncthreads();
    }
    if (tid == 0) { top[bh * NC + u] = ridx[0]; vals[ridx[0]] = -INFINITY; }
    __syncthreads();
  }
}

// ---------------- V mean over L ----------------
__global__ void vmean_kernel(const float* __restrict__ v, float* __restrict__ vmean) {
  int bh  = blockIdx.x;
  int tid = threadIdx.x;   // 256
  int e = tid & 15, g = tid >> 4;
  float s = 0.f;
  for (int l = g; l < SL; l += 16) s += v[(bh * SL + l) * EHD + e];
  __shared__ float red[256];
  red[tid] = s; __syncthreads();
  for (int st = 128; st >= 16; st >>= 1) {
    if (tid < st) red[tid] += red[tid + st];
    __syncthreads();
  }
  if (tid < EHD) vmean[bh * EHD + tid] = red[tid] * (1.0f / (float)SL);
}

// ---------------- ctx = broadcast vmean ----------------
__global__ void fillctx_kernel(const float* __restrict__ vmean, float* __restrict__ ctx) {
  int t = blockIdx.x * blockDim.x + threadIdx.x;
  if (t >= NBH * SL * EHD) return;
  int e  = t & 15;
  int bh = t >> 16;
  ctx[t] = vmean[bh * EHD + e];
}

// ---------------- full attention for top-27 queries ----------------
__global__ void attn_kernel(const float* __restrict__ q, const float* __restrict__ k,
                            const float* __restrict__ v, const int* __restrict__ top,
                            float* __restrict__ ctx) {
  int bid = blockIdx.x;        // bh*NC + u
  int bh  = bid / NC;
  int u   = bid - bh * NC;
  int tid = threadIdx.x;       // 256
  int qi  = top[bh * NC + u];
  __shared__ float qs[EHD];
  __shared__ float sc[SL];
  __shared__ float red[256];
  __shared__ float outv[EHD];
  if (tid < EHD) qs[tid] = q[(bh * SL + qi) * EHD + tid];
  __syncthreads();
  const float scale = 0.25f;   // 1/sqrt(16)
  float lmax = -INFINITY;
  for (int i = tid; i < SL; i += 256) {
    const float* krow = k + (bh * SL + i) * EHD;
    float s = 0.f;
#pragma unroll
    for (int e = 0; e < EHD; ++e) s += qs[e] * krow[e];
    s *= scale;
    sc[i] = s;
    lmax = fmaxf(lmax, s);
  }
  red[tid] = lmax; __syncthreads();
  for (int s = 128; s > 0; s >>= 1) {
    if (tid < s) red[tid] = fmaxf(red[tid], red[tid + s]);
    __syncthreads();
  }
  float mx = red[0];
  __syncthreads();
  float lsum = 0.f;
  float acc[EHD];
#pragma unroll
  for (int e = 0; e < EHD; ++e) acc[e] = 0.f;
  for (int i = tid; i < SL; i += 256) {
    float p = expf(sc[i] - mx);
    lsum += p;
    const float* vrow = v + (bh * SL + i) * EHD;
#pragma unroll
    for (int e = 0; e < EHD; ++e) acc[e] += p * vrow[e];
  }
  red[tid] = lsum; __syncthreads();
  for (int s = 128; s > 0; s >>= 1) {
    if (tid < s) red[tid] += red[tid + s];
    __syncthreads();
  }
  float denom = red[0];
  __syncthreads();
  for (int e = 0; e < EHD; ++e) {
    red[tid] = acc[e]; __syncthreads();
    for (int s = 128; s > 0; s >>= 1) {
      if (tid < s) red[tid] += red[tid + s];
      __syncthreads();
    }
    if (tid == 0) outv[e] = red[0];
    __syncthreads();
  }
  if (tid < EHD) ctx[(bh * SL + qi) * EHD + tid] = outv[tid] / denom;
}

// ---------------- O-proj + residual + LN1 ----------------
__global__ void oproj_ln_kernel(float* __restrict__ h, const float* __restrict__ ctx,
                                const float* __restrict__ Wo, const float* __restrict__ bo,
                                const float* __restrict__ lnw, const float* __restrict__ lnb,
                                int layer) {
  int row = blockIdx.x;
  int d   = threadIdx.x;    // 128
  int b = row >> 12, l = row & (SL - 1);
  __shared__ float cs[DM];
  __shared__ float red[DM];
  int hh = d >> 4, e = d & 15;
  cs[d] = ctx[((b * NH + hh) * SL + l) * EHD + e];
  __syncthreads();
  const float* w = Wo + (layer * DM + d) * DM;
  float a = bo[layer * DM + d];
  for (int i = 0; i < DM; ++i) a += cs[i] * w[i];
  float t = h[row * DM + d] + a;
  red[d] = t; __syncthreads();
  for (int s = 64; s > 0; s >>= 1) { if (d < s) red[d] += red[d + s]; __syncthreads(); }
  float mean = red[0] * (1.0f / (float)DM);
  __syncthreads();
  float c0 = t - mean;
  red[d] = c0 * c0; __syncthreads();
  for (int s = 64; s > 0; s >>= 1) { if (d < s) red[d] += red[d + s]; __syncthreads(); }
  float var = red[0] * (1.0f / (float)DM);
  float rstd = 1.0f / sqrtf(var + 1e-5f);
  h[row * DM + d] = c0 * rstd * lnw[layer * DM + d] + lnb[layer * DM + d];
}

// ---------------- FF1 + exact GELU ----------------
__global__ void ff1_kernel(const float* __restrict__ h, const float* __restrict__ W1,
                           const float* __restrict__ b1, float* __restrict__ y, int layer) {
  int row = blockIdx.x;
  int f   = threadIdx.x;    // 64
  __shared__ float hs[DM];
  hs[f] = h[row * DM + f];
  hs[f + 64] = h[row * DM + f + 64];
  __syncthreads();
  const float* w = W1 + (layer * DFF + f) * DM;
  float a = b1[layer * DFF + f];
  for (int i = 0; i < DM; ++i) a += hs[i] * w[i];
  float g = 0.5f * a * (1.0f + erff(a * 0.707106781186547524f));
  y[row * DFF + f] = g;
}

// ---------------- FF2 + residual + LN2 ----------------
__global__ void ff2_ln_kernel(float* __restrict__ h, const float* __restrict__ y,
                              const float* __restrict__ W2, const float* __restrict__ b2,
                              const float* __restrict__ lnw, const float* __restrict__ lnb,
                              int layer) {
  int row = blockIdx.x;
  int d   = threadIdx.x;    // 128
  __shared__ float ys[DFF];
  __shared__ float red[DM];
  if (d < DFF) ys[d] = y[row * DFF + d];
  __syncthreads();
  const float* w = W2 + (layer * DM + d) * DFF;
  float a = b2[layer * DM + d];
  for (int i = 0; i < DFF; ++i) a += ys[i] * w[i];
  float t = h[row * DM + d] + a;
  red[d] = t; __syncthreads();
  for (int s = 64; s > 0; s >>= 1) { if (d < s) red[d] += red[d + s]; __syncthreads(); }
  float mean = red[0] * (1.0f / (float)DM);
  __syncthreads();
  float c0 = t - mean;
  red[d] = c0 * c0; __syncthreads();
  for (int s = 64; s > 0; s >>= 1) { if (d < s) red[d] += red[d + s]; __syncthreads(); }
  float var = red[0] * (1.0f / (float)DM);
  float rstd = 1.0f / sqrtf(var + 1e-5f);
  h[row * DM + d] = c0 * rstd * lnw[layer * DM + d] + lnb[layer * DM + d];
}

// ---------------- final LN + projection (+ transpose store) ----------------
__global__ void final_kernel(const float* __restrict__ h, const float* __restrict__ lnw,
                             const float* __restrict__ lnb, const float* __restrict__ Wp,
                             const float* __restrict__ bp, float* __restrict__ out) {
  int row = blockIdx.x;
  int d   = threadIdx.x;    // 128
  int b = row >> 12, l = row & (SL - 1);
  __shared__ float red[DM];
  __shared__ float gs[DM];
  float t = h[row * DM + d];
  red[d] = t; __syncthreads();
  for (int s = 64; s > 0; s >>= 1) { if (d < s) red[d] += red[d + s]; __syncthreads(); }
  float mean = red[0] * (1.0f / (float)DM);
  __syncthreads();
  float c0 = t - mean;
  red[d] = c0 * c0; __syncthreads();
  for (int s = 64; s > 0; s >>= 1) { if (d < s) red[d] += red[d + s]; __syncthreads(); }
  float var = red[0] * (1.0f / (float)DM);
  float rstd = 1.0f / sqrtf(var + 1e-5f);
  gs[d] = c0 * rstd * lnw[d] + lnb[d];
  __syncthreads();
  float a = bp[d];
  for (int i = 0; i < DM; ++i) a += gs[i] * Wp[i * NREP + d];
  out[(b * NREP + d) * SL + l] = a;
}

// ---------------- launch ----------------
extern "C" void kernel_launch(void* const* d_in, const int* in_sizes, int n_in,
                              void* d_out, int out_size, void* d_ws, size_t ws_size,
                              hipStream_t stream) {
  const float* x   = (const float*)d_in[0];
  const float* Wq  = (const float*)d_in[1];
  const float* bq  = (const float*)d_in[2];
  const float* Wk  = (const float*)d_in[3];
  const float* bk  = (const float*)d_in[4];
  const float* Wv  = (const float*)d_in[5];
  const float* bv  = (const float*)d_in[6];
  const float* Wo  = (const float*)d_in[7];
  const float* bo  = (const float*)d_in[8];
  const float* W1  = (const float*)d_in[9];
  const float* b1  = (const float*)d_in[10];
  const float* W2  = (const float*)d_in[11];
  const float* b2  = (const float*)d_in[12];
  const float* ln1w = (const float*)d_in[13];
  const float* ln1b = (const float*)d_in[14];
  const float* ln2w = (const float*)d_in[15];
  const float* ln2b = (const float*)d_in[16];
  const float* lnfw = (const float*)d_in[17];
  const float* lnfb = (const float*)d_in[18];
  const float* Wp  = (const float*)d_in[19];
  const float* bp  = (const float*)d_in[20];
  float* out = (float*)d_out;

  float* ws = (float*)d_ws;
  float* h     = ws;                      // 4194304
  float* q     = ws + 4194304;            // 4194304
  float* k     = ws + 8388608;            // 4194304
  float* v     = ws + 12582912;           // 4194304
  float* ctx   = ws + 16777216;           // 4194304
  float* y     = ws + 20971520;           // 2097152
  float* M     = ws + 23068672;           // 262144
  float* vmean = ws + 23330816;           // 1024
  int*   top   = (int*)(ws + 23331840);   // 1728
  uint32_t* bits = (uint32_t*)(ws + 23333888); // 110592

  transpose_x_kernel<<<(NB * SL * DM + 255) / 256, 256, 0, stream>>>(x, h);

  for (int l = 0; l < NLAY; ++l) {
    gen_bits_kernel<<<(SL * NC + 255) / 256, 256, 0, stream>>>(bits, l);
    qkv_kernel<<<NROWS, DM, 0, stream>>>(h, Wq, bq, Wk, bk, Wv, bv, q, k, v, l);
    sampM_kernel<<<(NBH * SL + 255) / 256, 256, 0, stream>>>(q, k, bits, M);
    topk_kernel<<<NBH, 256, 0, stream>>>(M, top);
    vmean_kernel<<<NBH, 256, 0, stream>>>(v, vmean);
    fillctx_kernel<<<(NBH * SL * EHD + 255) / 256, 256, 0, stream>>>(vmean, ctx);
    attn_kernel<<<NBH * NC, 256, 0, stream>>>(q, k, v, top, ctx);
    oproj_ln_kernel<<<NROWS, DM, 0, stream>>>(h, ctx, Wo, bo, ln1w, ln1b, l);
    ff1_kernel<<<NROWS, DFF, 0, stream>>>(h, W1, b1, y, l);
    ff2_ln_kernel<<<NROWS, DM, 0, stream>>>(h, y, W2, b2, ln2w, ln2b, l);
  }

  final_kernel<<<NROWS, DM, 0, stream>>>(h, lnfw, lnfb, Wp, bp, out);
}

// Round 2
// 1842.912 us; speedup vs baseline: 4.6539x; 4.6539x over previous
//
#include <hip/hip_runtime.h>
#include <stdint.h>
#include <math.h>

#define DM   128
#define NH   8
#define EHD  16
#define NLAY 5
#define DFF  64
#define NREP 128
#define NB   8
#define SL   4096
#define NC   27
#define NBH  (NB*NH)      // 64
#define NROWS (NB*SL)     // 32768
#define TM   32

// ---------------- threefry2x32 (JAX-exact) ----------------
__device__ __forceinline__ uint32_t rotl32(uint32_t v, int d) {
  return (v << d) | (v >> (32 - d));
}

__device__ __forceinline__ void tf2x32(uint32_t k0, uint32_t k1,
                                       uint32_t x0, uint32_t x1,
                                       uint32_t &o0, uint32_t &o1) {
  uint32_t ks2 = k0 ^ k1 ^ 0x1BD11BDAu;
  x0 += k0; x1 += k1;
#define TFR(r) { x0 += x1; x1 = rotl32(x1, (r)); x1 ^= x0; }
  TFR(13) TFR(15) TFR(26) TFR(6)
  x0 += k1; x1 += ks2 + 1u;
  TFR(17) TFR(29) TFR(16) TFR(24)
  x0 += ks2; x1 += k0 + 2u;
  TFR(13) TFR(15) TFR(26) TFR(6)
  x0 += k0; x1 += k1 + 3u;
  TFR(17) TFR(29) TFR(16) TFR(24)
  x0 += k1; x1 += ks2 + 4u;
  TFR(13) TFR(15) TFR(26) TFR(6)
  x0 += ks2; x1 += k0 + 5u;
#undef TFR
  o0 = x0; o1 = x1;
}

__global__ void gen_bits_kernel(uint32_t* __restrict__ bits, int layer) {
  int i = blockIdx.x * blockDim.x + threadIdx.x;
  if (i >= SL * NC) return;
  uint32_t ka, kb, k2a, k2b, y0, y1;
  tf2x32(0u, 42u, 0u, (uint32_t)layer, ka, kb);   // fold_in
  tf2x32(ka, kb, 0u, 1u, k2a, k2b);               // split -> k2 (counter 1)
  tf2x32(k2a, k2b, 0u, (uint32_t)i, y0, y1);      // counter-mode bits
  bits[i] = y0 ^ y1;
}

// ---------------- x[b,d,l] -> h[b,l,d], LDS-tiled ----------------
__global__ __launch_bounds__(256) void transpose_x_kernel(const float* __restrict__ x,
                                                          float* __restrict__ h) {
  __shared__ float t[32][33];
  int tid = threadIdx.x;
  int tx = tid & 31, ty = tid >> 5;             // 32 x 8
  int l0 = blockIdx.x * 32, d0 = blockIdx.y * 32, b = blockIdx.z;
#pragma unroll
  for (int j = 0; j < 4; ++j) {
    int d = d0 + ty + 8 * j;
    t[ty + 8 * j][tx] = x[((size_t)b * DM + d) * SL + l0 + tx];
  }
  __syncthreads();
#pragma unroll
  for (int j = 0; j < 4; ++j) {
    int l = l0 + ty + 8 * j;
    h[((size_t)b * SL + l) * DM + d0 + tx] = t[tx][ty + 8 * j];
  }
}

// ---------------- QKV tiled GEMM ----------------
// grid (NROWS/TM, 3); block 256. Ws[k][n] (transposed W), hs[k][m].
__global__ __launch_bounds__(256) void gemm_qkv(const float* __restrict__ h,
    const float* __restrict__ Wq, const float* __restrict__ bq,
    const float* __restrict__ Wk, const float* __restrict__ bk,
    const float* __restrict__ Wv, const float* __restrict__ bv,
    float* __restrict__ q, float* __restrict__ k, float* __restrict__ v) {
  __shared__ float Ws[DM * DM];   // 64 KB
  __shared__ float hs[DM * TM];   // 16 KB
  int tid = threadIdx.x;
  int rb = blockIdx.x;
  const float* W; const float* bias; float* outp;
  if (blockIdx.y == 0)      { W = Wq; bias = bq; outp = q; }
  else if (blockIdx.y == 1) { W = Wk; bias = bk; outp = k; }
  else                      { W = Wv; bias = bv; outp = v; }
  for (int idx = tid; idx < DM * DM / 4; idx += 256) {
    int n = idx & 127, kg = idx >> 7;
    float4 w4 = *(const float4*)(W + (size_t)n * DM + kg * 4);
    Ws[(4 * kg + 0) * DM + n] = w4.x;
    Ws[(4 * kg + 1) * DM + n] = w4.y;
    Ws[(4 * kg + 2) * DM + n] = w4.z;
    Ws[(4 * kg + 3) * DM + n] = w4.w;
  }
  int row0 = rb * TM;
  for (int idx = tid; idx < TM * DM / 4; idx += 256) {
    int m = idx & (TM - 1), kg = idx >> 5;
    float4 h4 = *(const float4*)(h + (size_t)(row0 + m) * DM + kg * 4);
    hs[(4 * kg + 0) * TM + m] = h4.x;
    hs[(4 * kg + 1) * TM + m] = h4.y;
    hs[(4 * kg + 2) * TM + m] = h4.z;
    hs[(4 * kg + 3) * TM + m] = h4.w;
  }
  __syncthreads();
  int tc = tid & 15, tr = tid >> 4;
  float acc[16];
#pragma unroll
  for (int i = 0; i < 16; ++i) acc[i] = 0.f;
#pragma unroll 8
  for (int kk = 0; kk < DM; ++kk) {
    float2 hv = *(const float2*)(hs + kk * TM + 2 * tr);
    float4 w0 = *(const float4*)(Ws + kk * DM + 4 * tc);
    float4 w1 = *(const float4*)(Ws + kk * DM + 64 + 4 * tc);
    acc[0]  += hv.x * w0.x; acc[1]  += hv.x * w0.y; acc[2]  += hv.x * w0.z; acc[3]  += hv.x * w0.w;
    acc[4]  += hv.x * w1.x; acc[5]  += hv.x * w1.y; acc[6]  += hv.x * w1.z; acc[7]  += hv.x * w1.w;
    acc[8]  += hv.y * w0.x; acc[9]  += hv.y * w0.y; acc[10] += hv.y * w0.z; acc[11] += hv.y * w0.w;
    acc[12] += hv.y * w1.x; acc[13] += hv.y * w1.y; acc[14] += hv.y * w1.z; acc[15] += hv.y * w1.w;
  }
  float4 b0 = *(const float4*)(bias + 4 * tc);
  float4 b1 = *(const float4*)(bias + 64 + 4 * tc);
#pragma unroll
  for (int r = 0; r < 2; ++r) {
    int row = row0 + 2 * tr + r;
    int b = row >> 12, l = row & (SL - 1);
    int n0 = 4 * tc;
    float4 o0 = make_float4(acc[r*8+0] + b0.x, acc[r*8+1] + b0.y, acc[r*8+2] + b0.z, acc[r*8+3] + b0.w);
    *(float4*)(outp + ((size_t)(b * NH + (n0 >> 4)) * SL + l) * EHD + (n0 & 15)) = o0;
    int n1 = 64 + 4 * tc;
    float4 o1 = make_float4(acc[r*8+4] + b1.x, acc[r*8+5] + b1.y, acc[r*8+6] + b1.z, acc[r*8+7] + b1.w);
    *(float4*)(outp + ((size_t)(b * NH + (n1 >> 4)) * SL + l) * EHD + (n1 & 15)) = o1;
  }
}

// ---------------- O-proj + residual + LN1 (tiled GEMM, fused) ----------------
__global__ __launch_bounds__(256) void gemm_oln(float* __restrict__ h,
    const float* __restrict__ ctx, const float* __restrict__ W,
    const float* __restrict__ bias, const float* __restrict__ gw,
    const float* __restrict__ gb) {
  __shared__ float Ws[DM * DM];
  __shared__ float cs[DM * TM];
  int tid = threadIdx.x;
  int rb = blockIdx.x;
  for (int idx = tid; idx < DM * DM / 4; idx += 256) {
    int n = idx & 127, kg = idx >> 7;
    float4 w4 = *(const float4*)(W + (size_t)n * DM + kg * 4);
    Ws[(4 * kg + 0) * DM + n] = w4.x;
    Ws[(4 * kg + 1) * DM + n] = w4.y;
    Ws[(4 * kg + 2) * DM + n] = w4.z;
    Ws[(4 * kg + 3) * DM + n] = w4.w;
  }
  int row0 = rb * TM;
  for (int idx = tid; idx < TM * DM / 4; idx += 256) {
    int m = idx & (TM - 1), kg = idx >> 5;
    int row = row0 + m;
    int b = row >> 12, l = row & (SL - 1);
    int head = kg >> 2, e0 = (kg & 3) * 4;
    float4 c4 = *(const float4*)(ctx + ((size_t)(b * NH + head) * SL + l) * EHD + e0);
    cs[(4 * kg + 0) * TM + m] = c4.x;
    cs[(4 * kg + 1) * TM + m] = c4.y;
    cs[(4 * kg + 2) * TM + m] = c4.z;
    cs[(4 * kg + 3) * TM + m] = c4.w;
  }
  __syncthreads();
  int tc = tid & 15, tr = tid >> 4;
  float acc[16];
#pragma unroll
  for (int i = 0; i < 16; ++i) acc[i] = 0.f;
#pragma unroll 8
  for (int kk = 0; kk < DM; ++kk) {
    float2 hv = *(const float2*)(cs + kk * TM + 2 * tr);
    float4 w0 = *(const float4*)(Ws + kk * DM + 4 * tc);
    float4 w1 = *(const float4*)(Ws + kk * DM + 64 + 4 * tc);
    acc[0]  += hv.x * w0.x; acc[1]  += hv.x * w0.y; acc[2]  += hv.x * w0.z; acc[3]  += hv.x * w0.w;
    acc[4]  += hv.x * w1.x; acc[5]  += hv.x * w1.y; acc[6]  += hv.x * w1.z; acc[7]  += hv.x * w1.w;
    acc[8]  += hv.y * w0.x; acc[9]  += hv.y * w0.y; acc[10] += hv.y * w0.z; acc[11] += hv.y * w0.w;
    acc[12] += hv.y * w1.x; acc[13] += hv.y * w1.y; acc[14] += hv.y * w1.z; acc[15] += hv.y * w1.w;
  }
  float4 bo0 = *(const float4*)(bias + 4 * tc);
  float4 bo1 = *(const float4*)(bias + 64 + 4 * tc);
  float4 g0 = *(const float4*)(gw + 4 * tc);
  float4 g1 = *(const float4*)(gw + 64 + 4 * tc);
  float4 e0v = *(const float4*)(gb + 4 * tc);
  float4 e1v = *(const float4*)(gb + 64 + 4 * tc);
#pragma unroll
  for (int r = 0; r < 2; ++r) {
    int row = row0 + 2 * tr + r;
    float4 res0 = *(const float4*)(h + (size_t)row * DM + 4 * tc);
    float4 res1 = *(const float4*)(h + (size_t)row * DM + 64 + 4 * tc);
    float t0 = acc[r*8+0] + bo0.x + res0.x;
    float t1 = acc[r*8+1] + bo0.y + res0.y;
    float t2 = acc[r*8+2] + bo0.z + res0.z;
    float t3 = acc[r*8+3] + bo0.w + res0.w;
    float t4 = acc[r*8+4] + bo1.x + res1.x;
    float t5 = acc[r*8+5] + bo1.y + res1.y;
    float t6 = acc[r*8+6] + bo1.z + res1.z;
    float t7 = acc[r*8+7] + bo1.w + res1.w;
    float s = t0+t1+t2+t3+t4+t5+t6+t7;
    s += __shfl_xor(s, 1, 16); s += __shfl_xor(s, 2, 16);
    s += __shfl_xor(s, 4, 16); s += __shfl_xor(s, 8, 16);
    float mean = s * (1.0f / (float)DM);
    float d0 = t0-mean, d1 = t1-mean, d2 = t2-mean, d3 = t3-mean;
    float d4 = t4-mean, d5 = t5-mean, d6 = t6-mean, d7 = t7-mean;
    float ss = d0*d0+d1*d1+d2*d2+d3*d3+d4*d4+d5*d5+d6*d6+d7*d7;
    ss += __shfl_xor(ss, 1, 16); ss += __shfl_xor(ss, 2, 16);
    ss += __shfl_xor(ss, 4, 16); ss += __shfl_xor(ss, 8, 16);
    float rstd = 1.0f / sqrtf(ss * (1.0f / (float)DM) + 1e-5f);
    float4 o0 = make_float4(d0*rstd*g0.x + e0v.x, d1*rstd*g0.y + e0v.y,
                            d2*rstd*g0.z + e0v.z, d3*rstd*g0.w + e0v.w);
    float4 o1 = make_float4(d4*rstd*g1.x + e1v.x, d5*rstd*g1.y + e1v.y,
                            d6*rstd*g1.z + e1v.z, d7*rstd*g1.w + e1v.w);
    *(float4*)(h + (size_t)row * DM + 4 * tc) = o0;
    *(float4*)(h + (size_t)row * DM + 64 + 4 * tc) = o1;
  }
}

// ---------------- FF1 + exact GELU (tiled GEMM) ----------------
__global__ __launch_bounds__(256) void gemm_ff1(const float* __restrict__ h,
    const float* __restrict__ W, const float* __restrict__ bias,
    float* __restrict__ y) {
  __shared__ float Ws[DM * DFF];   // 32 KB  Ws[k][n]
  __shared__ float hs[DM * TM];    // 16 KB
  int tid = threadIdx.x;
  int rb = blockIdx.x;
  for (int idx = tid; idx < DFF * DM / 4; idx += 256) {
    int n = idx & 63, kg = idx >> 6;
    float4 w4 = *(const float4*)(W + (size_t)n * DM + kg * 4);
    Ws[(4 * kg + 0) * DFF + n] = w4.x;
    Ws[(4 * kg + 1) * DFF + n] = w4.y;
    Ws[(4 * kg + 2) * DFF + n] = w4.z;
    Ws[(4 * kg + 3) * DFF + n] = w4.w;
  }
  int row0 = rb * TM;
  for (int idx = tid; idx < TM * DM / 4; idx += 256) {
    int m = idx & (TM - 1), kg = idx >> 5;
    float4 h4 = *(const float4*)(h + (size_t)(row0 + m) * DM + kg * 4);
    hs[(4 * kg + 0) * TM + m] = h4.x;
    hs[(4 * kg + 1) * TM + m] = h4.y;
    hs[(4 * kg + 2) * TM + m] = h4.z;
    hs[(4 * kg + 3) * TM + m] = h4.w;
  }
  __syncthreads();
  int tc = tid & 15, tr = tid >> 4;
  float acc[8];
#pragma unroll
  for (int i = 0; i < 8; ++i) acc[i] = 0.f;
#pragma unroll 8
  for (int kk = 0; kk < DM; ++kk) {
    float2 hv = *(const float2*)(hs + kk * TM + 2 * tr);
    float4 w0 = *(const float4*)(Ws + kk * DFF + 4 * tc);
    acc[0] += hv.x * w0.x; acc[1] += hv.x * w0.y; acc[2] += hv.x * w0.z; acc[3] += hv.x * w0.w;
    acc[4] += hv.y * w0.x; acc[5] += hv.y * w0.y; acc[6] += hv.y * w0.z; acc[7] += hv.y * w0.w;
  }
  float4 b0 = *(const float4*)(bias + 4 * tc);
#pragma unroll
  for (int r = 0; r < 2; ++r) {
    int row = row0 + 2 * tr + r;
    float a0 = acc[r*4+0] + b0.x, a1 = acc[r*4+1] + b0.y;
    float a2 = acc[r*4+2] + b0.z, a3 = acc[r*4+3] + b0.w;
    const float is2 = 0.707106781186547524f;
    float4 o = make_float4(0.5f*a0*(1.f+erff(a0*is2)), 0.5f*a1*(1.f+erff(a1*is2)),
                           0.5f*a2*(1.f+erff(a2*is2)), 0.5f*a3*(1.f+erff(a3*is2)));
    *(float4*)(y + (size_t)row * DFF + 4 * tc) = o;
  }
}

// ---------------- FF2 + residual + LN2 (tiled GEMM, fused) ----------------
__global__ __launch_bounds__(256) void gemm_ff2ln(float* __restrict__ h,
    const float* __restrict__ y, const float* __restrict__ W,
    const float* __restrict__ bias, const float* __restrict__ gw,
    const float* __restrict__ gb) {
  __shared__ float Ws[DFF * DM];   // 32 KB  Ws[k2][n]
  __shared__ float ys[DFF * TM];   // 8 KB
  int tid = threadIdx.x;
  int rb = blockIdx.x;
  for (int idx = tid; idx < DM * DFF / 4; idx += 256) {
    int n = idx & 127, kg = idx >> 7;   // kg 0..15
    float4 w4 = *(const float4*)(W + (size_t)n * DFF + kg * 4);
    Ws[(4 * kg + 0) * DM + n] = w4.x;
    Ws[(4 * kg + 1) * DM + n] = w4.y;
    Ws[(4 * kg + 2) * DM + n] = w4.z;
    Ws[(4 * kg + 3) * DM + n] = w4.w;
  }
  int row0 = rb * TM;
  for (int idx = tid; idx < TM * DFF / 4; idx += 256) {
    int m = idx & (TM - 1), kg = idx >> 5;   // kg 0..15
    float4 y4 = *(const float4*)(y + (size_t)(row0 + m) * DFF + kg * 4);
    ys[(4 * kg + 0) * TM + m] = y4.x;
    ys[(4 * kg + 1) * TM + m] = y4.y;
    ys[(4 * kg + 2) * TM + m] = y4.z;
    ys[(4 * kg + 3) * TM + m] = y4.w;
  }
  __syncthreads();
  int tc = tid & 15, tr = tid >> 4;
  float acc[16];
#pragma unroll
  for (int i = 0; i < 16; ++i) acc[i] = 0.f;
#pragma unroll 8
  for (int kk = 0; kk < DFF; ++kk) {
    float2 hv = *(const float2*)(ys + kk * TM + 2 * tr);
    float4 w0 = *(const float4*)(Ws + kk * DM + 4 * tc);
    float4 w1 = *(const float4*)(Ws + kk * DM + 64 + 4 * tc);
    acc[0]  += hv.x * w0.x; acc[1]  += hv.x * w0.y; acc[2]  += hv.x * w0.z; acc[3]  += hv.x * w0.w;
    acc[4]  += hv.x * w1.x; acc[5]  += hv.x * w1.y; acc[6]  += hv.x * w1.z; acc[7]  += hv.x * w1.w;
    acc[8]  += hv.y * w0.x; acc[9]  += hv.y * w0.y; acc[10] += hv.y * w0.z; acc[11] += hv.y * w0.w;
    acc[12] += hv.y * w1.x; acc[13] += hv.y * w1.y; acc[14] += hv.y * w1.z; acc[15] += hv.y * w1.w;
  }
  float4 bo0 = *(const float4*)(bias + 4 * tc);
  float4 bo1 = *(const float4*)(bias + 64 + 4 * tc);
  float4 g0 = *(const float4*)(gw + 4 * tc);
  float4 g1 = *(const float4*)(gw + 64 + 4 * tc);
  float4 e0v = *(const float4*)(gb + 4 * tc);
  float4 e1v = *(const float4*)(gb + 64 + 4 * tc);
#pragma unroll
  for (int r = 0; r < 2; ++r) {
    int row = row0 + 2 * tr + r;
    float4 res0 = *(const float4*)(h + (size_t)row * DM + 4 * tc);
    float4 res1 = *(const float4*)(h + (size_t)row * DM + 64 + 4 * tc);
    float t0 = acc[r*8+0] + bo0.x + res0.x;
    float t1 = acc[r*8+1] + bo0.y + res0.y;
    float t2 = acc[r*8+2] + bo0.z + res0.z;
    float t3 = acc[r*8+3] + bo0.w + res0.w;
    float t4 = acc[r*8+4] + bo1.x + res1.x;
    float t5 = acc[r*8+5] + bo1.y + res1.y;
    float t6 = acc[r*8+6] + bo1.z + res1.z;
    float t7 = acc[r*8+7] + bo1.w + res1.w;
    float s = t0+t1+t2+t3+t4+t5+t6+t7;
    s += __shfl_xor(s, 1, 16); s += __shfl_xor(s, 2, 16);
    s += __shfl_xor(s, 4, 16); s += __shfl_xor(s, 8, 16);
    float mean = s * (1.0f / (float)DM);
    float d0 = t0-mean, d1 = t1-mean, d2 = t2-mean, d3 = t3-mean;
    float d4 = t4-mean, d5 = t5-mean, d6 = t6-mean, d7 = t7-mean;
    float ss = d0*d0+d1*d1+d2*d2+d3*d3+d4*d4+d5*d5+d6*d6+d7*d7;
    ss += __shfl_xor(ss, 1, 16); ss += __shfl_xor(ss, 2, 16);
    ss += __shfl_xor(ss, 4, 16); ss += __shfl_xor(ss, 8, 16);
    float rstd = 1.0f / sqrtf(ss * (1.0f / (float)DM) + 1e-5f);
    float4 o0 = make_float4(d0*rstd*g0.x + e0v.x, d1*rstd*g0.y + e0v.y,
                            d2*rstd*g0.z + e0v.z, d3*rstd*g0.w + e0v.w);
    float4 o1 = make_float4(d4*rstd*g1.x + e1v.x, d5*rstd*g1.y + e1v.y,
                            d6*rstd*g1.z + e1v.z, d7*rstd*g1.w + e1v.w);
    *(float4*)(h + (size_t)row * DM + 4 * tc) = o0;
    *(float4*)(h + (size_t)row * DM + 64 + 4 * tc) = o1;
  }
}

// ---------------- final: LN -> proj -> transposed store ----------------
__global__ __launch_bounds__(256) void gemm_final(const float* __restrict__ h,
    const float* __restrict__ lnw, const float* __restrict__ lnb,
    const float* __restrict__ Wp, const float* __restrict__ bp,
    float* __restrict__ out) {
  __shared__ float Ws[DM * DM];   // 64 KB (also scratch for LN partials)
  __shared__ float hs[DM * TM];   // 16 KB
  int tid = threadIdx.x;
  int rb = blockIdx.x;
  int row0 = rb * TM;
  for (int idx = tid; idx < TM * DM / 4; idx += 256) {
    int m = idx & (TM - 1), kg = idx >> 5;
    float4 h4 = *(const float4*)(h + (size_t)(row0 + m) * DM + kg * 4);
    hs[(4 * kg + 0) * TM + m] = h4.x;
    hs[(4 * kg + 1) * TM + m] = h4.y;
    hs[(4 * kg + 2) * TM + m] = h4.z;
    hs[(4 * kg + 3) * TM + m] = h4.w;
  }
  __syncthreads();
  // LayerNorm rows of hs in-place. thread: m = tid>>3 (row), g = tid&7.
  {
    int m = tid >> 3, g = tid & 7;
    float part = 0.f;
#pragma unroll
    for (int i = 0; i < 16; ++i) part += hs[(g * 16 + i) * TM + m];
    Ws[m * 8 + g] = part;
    __syncthreads();
    float mean = 0.f;
#pragma unroll
    for (int gg = 0; gg < 8; ++gg) mean += Ws[m * 8 + gg];
    mean *= (1.0f / (float)DM);
    __syncthreads();
    float p2 = 0.f;
#pragma unroll
    for (int i = 0; i < 16; ++i) {
      float d = hs[(g * 16 + i) * TM + m] - mean;
      p2 += d * d;
    }
    Ws[m * 8 + g] = p2;
    __syncthreads();
    float var = 0.f;
#pragma unroll
    for (int gg = 0; gg < 8; ++gg) var += Ws[m * 8 + gg];
    var *= (1.0f / (float)DM);
    float rstd = 1.0f / sqrtf(var + 1e-5f);
#pragma unroll
    for (int i = 0; i < 16; ++i) {
      int kk = g * 16 + i;
      hs[kk * TM + m] = (hs[kk * TM + m] - mean) * rstd * lnw[kk] + lnb[kk];
    }
    __syncthreads();
  }
  // stage Wp (already k-major: Wp[k*NREP + n])
  for (int idx = tid; idx < DM * NREP / 4; idx += 256) {
    float4 w4 = *(const float4*)(Wp + (size_t)idx * 4);
    *(float4*)(Ws + (size_t)idx * 4) = w4;
  }
  __syncthreads();
  int tc = tid & 15, tr = tid >> 4;
  float acc[16];
#pragma unroll
  for (int i = 0; i < 16; ++i) acc[i] = 0.f;
#pragma unroll 8
  for (int kk = 0; kk < DM; ++kk) {
    float2 hv = *(const float2*)(hs + kk * TM + 2 * tr);
    float4 w0 = *(const float4*)(Ws + kk * NREP + 4 * tc);
    float4 w1 = *(const float4*)(Ws + kk * NREP + 64 + 4 * tc);
    acc[0]  += hv.x * w0.x; acc[1]  += hv.x * w0.y; acc[2]  += hv.x * w0.z; acc[3]  += hv.x * w0.w;
    acc[4]  += hv.x * w1.x; acc[5]  += hv.x * w1.y; acc[6]  += hv.x * w1.z; acc[7]  += hv.x * w1.w;
    acc[8]  += hv.y * w0.x; acc[9]  += hv.y * w0.y; acc[10] += hv.y * w0.z; acc[11] += hv.y * w0.w;
    acc[12] += hv.y * w1.x; acc[13] += hv.y * w1.y; acc[14] += hv.y * w1.z; acc[15] += hv.y * w1.w;
  }
  float4 b0 = *(const float4*)(bp + 4 * tc);
  float4 b1 = *(const float4*)(bp + 64 + 4 * tc);
#pragma unroll
  for (int r = 0; r < 2; ++r) {
    int row = row0 + 2 * tr + r;
    int b = row >> 12, l = row & (SL - 1);
    out[((size_t)(b * NREP + 4*tc + 0)) * SL + l] = acc[r*8+0] + b0.x;
    out[((size_t)(b * NREP + 4*tc + 1)) * SL + l] = acc[r*8+1] + b0.y;
    out[((size_t)(b * NREP + 4*tc + 2)) * SL + l] = acc[r*8+2] + b0.z;
    out[((size_t)(b * NREP + 4*tc + 3)) * SL + l] = acc[r*8+3] + b0.w;
    out[((size_t)(b * NREP + 64 + 4*tc + 0)) * SL + l] = acc[r*8+4] + b1.x;
    out[((size_t)(b * NREP + 64 + 4*tc + 1)) * SL + l] = acc[r*8+5] + b1.y;
    out[((size_t)(b * NREP + 64 + 4*tc + 2)) * SL + l] = acc[r*8+6] + b1.z;
    out[((size_t)(b * NREP + 64 + 4*tc + 3)) * SL + l] = acc[r*8+7] + b1.w;
  }
}

// ---------------- sampled scores -> M (XCD-local, vectorized) ----------------
__global__ __launch_bounds__(256) void sampM_kernel(const float* __restrict__ q,
    const float* __restrict__ k, const uint32_t* __restrict__ bits,
    float* __restrict__ M) {
  int tid = threadIdx.x;
  int bh = blockIdx.x & 63;          // bh%8 == blockIdx%8 -> XCD-local K
  int chunk = blockIdx.x >> 6;
  int l = chunk * 256 + tid;
  const float* qr = q + ((size_t)bh * SL + l) * EHD;
  float4 q0 = *(const float4*)(qr + 0);
  float4 q1 = *(const float4*)(qr + 4);
  float4 q2 = *(const float4*)(qr + 8);
  float4 q3 = *(const float4*)(qr + 12);
  const uint32_t* bl = bits + (size_t)l * NC;
  float mx = -INFINITY, sm = 0.f;
  for (int u = 0; u < NC; ++u) {
    int ki = (int)(bl[u] & (SL - 1));
    const float* kr = k + ((size_t)bh * SL + ki) * EHD;
    float4 k0 = *(const float4*)(kr + 0);
    float4 k1 = *(const float4*)(kr + 4);
    float4 k2 = *(const float4*)(kr + 8);
    float4 k3 = *(const float4*)(kr + 12);
    float s = q0.x*k0.x + q0.y*k0.y + q0.z*k0.z + q0.w*k0.w
            + q1.x*k1.x + q1.y*k1.y + q1.z*k1.z + q1.w*k1.w
            + q2.x*k2.x + q2.y*k2.y + q2.z*k2.z + q2.w*k2.w
            + q3.x*k3.x + q3.y*k3.y + q3.z*k3.z + q3.w*k3.w;
    mx = fmaxf(mx, s);
    sm += s;
  }
  M[(size_t)bh * SL + l] = mx - sm * (1.0f / (float)SL);
}

// ---------------- top-k (iterative argmax, stable ties) ----------------
__global__ void topk_kernel(const float* __restrict__ M, int* __restrict__ top) {
  int bh  = blockIdx.x;
  int tid = threadIdx.x;   // 256
  __shared__ float vals[SL];
  __shared__ float rmax[256];
  __shared__ int   ridx[256];
  for (int i = tid; i < SL; i += 256) vals[i] = M[(size_t)bh * SL + i];
  __syncthreads();
  for (int u = 0; u < NC; ++u) {
    float bm = -INFINITY; int bi = SL;
    for (int i = tid; i < SL; i += 256) {
      float vv = vals[i];
      if (vv > bm) { bm = vv; bi = i; }
    }
    rmax[tid] = bm; ridx[tid] = bi;
    __syncthreads();
    for (int s = 128; s > 0; s >>= 1) {
      if (tid < s) {
        float v2 = rmax[tid + s]; int i2 = ridx[tid + s];
        if (v2 > rmax[tid] || (v2 == rmax[tid] && i2 < ridx[tid])) {
          rmax[tid] = v2; ridx[tid] = i2;
        }
      }
      __syncthreads();
    }
    if (tid == 0) { top[bh * NC + u] = ridx[0]; vals[ridx[0]] = -INFINITY; }
    __syncthreads();
  }
}

// ---------------- V mean over L ----------------
__global__ void vmean_kernel(const float* __restrict__ v, float* __restrict__ vmean) {
  int bh  = blockIdx.x;
  int tid = threadIdx.x;   // 256
  int e = tid & 15, g = tid >> 4;
  float s = 0.f;
  for (int l = g; l < SL; l += 16) s += v[((size_t)bh * SL + l) * EHD + e];
  __shared__ float red[256];
  red[tid] = s; __syncthreads();
  for (int st = 128; st >= 16; st >>= 1) {
    if (tid < st) red[tid] += red[tid + st];
    __syncthreads();
  }
  if (tid < EHD) vmean[bh * EHD + tid] = red[tid] * (1.0f / (float)SL);
}

// ---------------- ctx = broadcast vmean (float4) ----------------
__global__ void fillctx_kernel(const float* __restrict__ vmean, float* __restrict__ ctx) {
  int t = blockIdx.x * blockDim.x + threadIdx.x;
  if (t >= NBH * SL * 4) return;
  int e0 = (t & 3) * 4;
  int bh = t >> 14;
  *(float4*)(ctx + (size_t)t * 4) = *(const float4*)(vmean + bh * EHD + e0);
}

// ---------------- full attention for top-27 queries ----------------
__global__ __launch_bounds__(256) void attn_kernel(const float* __restrict__ q,
    const float* __restrict__ k, const float* __restrict__ v,
    const int* __restrict__ top, float* __restrict__ ctx) {
  int bid = blockIdx.x;
  int bh = bid & 63, u = bid >> 6;     // XCD-local K/V
  int tid = threadIdx.x;               // 256
  int wave = tid >> 6, lane = tid & 63;
  int qi = top[bh * NC + u];
  __shared__ float sc[SL];
  __shared__ float red[64];
  const float* qr = q + ((size_t)bh * SL + qi) * EHD;
  float4 q0 = *(const float4*)(qr + 0);
  float4 q1 = *(const float4*)(qr + 4);
  float4 q2 = *(const float4*)(qr + 8);
  float4 q3 = *(const float4*)(qr + 12);
  const float scale = 0.25f;
  float lmax = -INFINITY;
  for (int i = tid; i < SL; i += 256) {
    const float* kr = k + ((size_t)bh * SL + i) * EHD;
    float4 k0 = *(const float4*)(kr + 0);
    float4 k1 = *(const float4*)(kr + 4);
    float4 k2 = *(const float4*)(kr + 8);
    float4 k3 = *(const float4*)(kr + 12);
    float s = q0.x*k0.x + q0.y*k0.y + q0.z*k0.z + q0.w*k0.w
            + q1.x*k1.x + q1.y*k1.y + q1.z*k1.z + q1.w*k1.w
            + q2.x*k2.x + q2.y*k2.y + q2.z*k2.z + q2.w*k2.w
            + q3.x*k3.x + q3.y*k3.y + q3.z*k3.z + q3.w*k3.w;
    s *= scale;
    sc[i] = s;
    lmax = fmaxf(lmax, s);
  }
#pragma unroll
  for (int off = 32; off > 0; off >>= 1) lmax = fmaxf(lmax, __shfl_xor(lmax, off, 64));
  if (lane == 0) red[wave] = lmax;
  __syncthreads();
  float mx = fmaxf(fmaxf(red[0], red[1]), fmaxf(red[2], red[3]));
  float lsum = 0.f;
  float acc[EHD];
#pragma unroll
  for (int e = 0; e < EHD; ++e) acc[e] = 0.f;
  for (int i = tid; i < SL; i += 256) {
    float p = expf(sc[i] - mx);
    lsum += p;
    const float* vr = v + ((size_t)bh * SL + i) * EHD;
    float4 v0 = *(const float4*)(vr + 0);
    float4 v1 = *(const float4*)(vr + 4);
    float4 v2 = *(const float4*)(vr + 8);
    float4 v3 = *(const float4*)(vr + 12);
    acc[0] += p*v0.x; acc[1] += p*v0.y; acc[2]  += p*v0.z; acc[3]  += p*v0.w;
    acc[4] += p*v1.x; acc[5] += p*v1.y; acc[6]  += p*v1.z; acc[7]  += p*v1.w;
    acc[8] += p*v2.x; acc[9] += p*v2.y; acc[10] += p*v2.z; acc[11] += p*v2.w;
    acc[12] += p*v3.x; acc[13] += p*v3.y; acc[14] += p*v3.z; acc[15] += p*v3.w;
  }
  __syncthreads();   // all reads of red[] for mx done
#pragma unroll
  for (int off = 32; off > 0; off >>= 1) lsum += __shfl_xor(lsum, off, 64);
  if (lane == 0) red[wave] = lsum;
  __syncthreads();
  float denom = red[0] + red[1] + red[2] + red[3];
  __syncthreads();   // denom read before red reuse
#pragma unroll
  for (int e = 0; e < EHD; ++e) {
    float vv = acc[e];
#pragma unroll
    for (int off = 32; off > 0; off >>= 1) vv += __shfl_xor(vv, off, 64);
    if (lane == 0) red[wave * 16 + e] = vv;
  }
  __syncthreads();
  if (tid < EHD) {
    float o = red[tid] + red[16 + tid] + red[32 + tid] + red[48 + tid];
    ctx[((size_t)bh * SL + qi) * EHD + tid] = o / denom;
  }
}

// ---------------- launch ----------------
extern "C" void kernel_launch(void* const* d_in, const int* in_sizes, int n_in,
                              void* d_out, int out_size, void* d_ws, size_t ws_size,
                              hipStream_t stream) {
  const float* x   = (const float*)d_in[0];
  const float* Wq  = (const float*)d_in[1];
  const float* bq  = (const float*)d_in[2];
  const float* Wk  = (const float*)d_in[3];
  const float* bk  = (const float*)d_in[4];
  const float* Wv  = (const float*)d_in[5];
  const float* bv  = (const float*)d_in[6];
  const float* Wo  = (const float*)d_in[7];
  const float* bo  = (const float*)d_in[8];
  const float* W1  = (const float*)d_in[9];
  const float* b1  = (const float*)d_in[10];
  const float* W2  = (const float*)d_in[11];
  const float* b2  = (const float*)d_in[12];
  const float* ln1w = (const float*)d_in[13];
  const float* ln1b = (const float*)d_in[14];
  const float* ln2w = (const float*)d_in[15];
  const float* ln2b = (const float*)d_in[16];
  const float* lnfw = (const float*)d_in[17];
  const float* lnfb = (const float*)d_in[18];
  const float* Wp  = (const float*)d_in[19];
  const float* bp  = (const float*)d_in[20];
  float* out = (float*)d_out;

  float* ws = (float*)d_ws;
  float* h     = ws;                      // 4194304
  float* q     = ws + 4194304;            // 4194304
  float* k     = ws + 8388608;            // 4194304
  float* v     = ws + 12582912;           // 4194304
  float* ctx   = ws + 16777216;           // 4194304
  float* y     = ws + 20971520;           // 2097152
  float* M     = ws + 23068672;           // 262144
  float* vmean = ws + 23330816;           // 1024
  int*   top   = (int*)(ws + 23331840);   // 1728
  uint32_t* bits = (uint32_t*)(ws + 23333888); // 110592

  transpose_x_kernel<<<dim3(SL / 32, DM / 32, NB), 256, 0, stream>>>(x, h);

  for (int l = 0; l < NLAY; ++l) {
    gen_bits_kernel<<<(SL * NC + 255) / 256, 256, 0, stream>>>(bits, l);
    gemm_qkv<<<dim3(NROWS / TM, 3), 256, 0, stream>>>(
        h, Wq + (size_t)l * DM * DM, bq + l * DM,
        Wk + (size_t)l * DM * DM, bk + l * DM,
        Wv + (size_t)l * DM * DM, bv + l * DM, q, k, v);
    sampM_kernel<<<NBH * SL / 256, 256, 0, stream>>>(q, k, bits, M);
    topk_kernel<<<NBH, 256, 0, stream>>>(M, top);
    vmean_kernel<<<NBH, 256, 0, stream>>>(v, vmean);
    fillctx_kernel<<<(NBH * SL * 4 + 255) / 256, 256, 0, stream>>>(vmean, ctx);
    attn_kernel<<<NBH * NC, 256, 0, stream>>>(q, k, v, top, ctx);
    gemm_oln<<<NROWS / TM, 256, 0, stream>>>(
        h, ctx, Wo + (size_t)l * DM * DM, bo + l * DM,
        ln1w + l * DM, ln1b + l * DM);
    gemm_ff1<<<NROWS / TM, 256, 0, stream>>>(
        h, W1 + (size_t)l * DFF * DM, b1 + l * DFF, y);
    gemm_ff2ln<<<NROWS / TM, 256, 0, stream>>>(
        h, y, W2 + (size_t)l * DM * DFF, b2 + l * DM,
        ln2w + l * DM, ln2b + l * DM);
  }

  gemm_final<<<NROWS / TM, 256, 0, stream>>>(h, lnfw, lnfb, Wp, bp, out);
}

// Round 4
// 1403.528 us; speedup vs baseline: 6.1108x; 1.3131x over previous
//
#include <hip/hip_runtime.h>
#include <stdint.h>
#include <math.h>

#define DM   128
#define NH   8
#define EHD  16
#define NLAY 5
#define DFF  64
#define NREP 128
#define NB   8
#define SL   4096
#define NC   27
#define NBH  (NB*NH)      // 64
#define NROWS (NB*SL)     // 32768

typedef _Float16 f16;
typedef f16 f16x8 __attribute__((ext_vector_type(8)));
typedef float f32x16 __attribute__((ext_vector_type(16)));

// ---------------- threefry2x32 (JAX-exact) ----------------
__device__ __forceinline__ uint32_t rotl32(uint32_t v, int d) {
  return (v << d) | (v >> (32 - d));
}

__device__ __forceinline__ void tf2x32(uint32_t k0, uint32_t k1,
                                       uint32_t x0, uint32_t x1,
                                       uint32_t &o0, uint32_t &o1) {
  uint32_t ks2 = k0 ^ k1 ^ 0x1BD11BDAu;
  x0 += k0; x1 += k1;
#define TFR(r) { x0 += x1; x1 = rotl32(x1, (r)); x1 ^= x0; }
  TFR(13) TFR(15) TFR(26) TFR(6)
  x0 += k1; x1 += ks2 + 1u;
  TFR(17) TFR(29) TFR(16) TFR(24)
  x0 += ks2; x1 += k0 + 2u;
  TFR(13) TFR(15) TFR(26) TFR(6)
  x0 += k0; x1 += k1 + 3u;
  TFR(17) TFR(29) TFR(16) TFR(24)
  x0 += k1; x1 += ks2 + 4u;
  TFR(13) TFR(15) TFR(26) TFR(6)
  x0 += ks2; x1 += k0 + 5u;
#undef TFR
  o0 = x0; o1 = x1;
}

__global__ void gen_bits_kernel(uint32_t* __restrict__ bits, int layer) {
  int i = blockIdx.x * blockDim.x + threadIdx.x;
  if (i >= SL * NC) return;
  uint32_t ka, kb, k2a, k2b, y0, y1;
  tf2x32(0u, 42u, 0u, (uint32_t)layer, ka, kb);
  tf2x32(ka, kb, 0u, 1u, k2a, k2b);
  tf2x32(k2a, k2b, 0u, (uint32_t)i, y0, y1);
  bits[i] = y0 ^ y1;
}

// ---------------- x[b,d,l] -> h[b,l,d], LDS-tiled ----------------
__global__ __launch_bounds__(256) void transpose_x_kernel(const float* __restrict__ x,
                                                          float* __restrict__ h) {
  __shared__ float t[32][33];
  int tid = threadIdx.x;
  int tx = tid & 31, ty = tid >> 5;
  int l0 = blockIdx.x * 32, d0 = blockIdx.y * 32, b = blockIdx.z;
#pragma unroll
  for (int j = 0; j < 4; ++j) {
    int d = d0 + ty + 8 * j;
    t[ty + 8 * j][tx] = x[((size_t)b * DM + d) * SL + l0 + tx];
  }
  __syncthreads();
#pragma unroll
  for (int j = 0; j < 4; ++j) {
    int l = l0 + ty + 8 * j;
    h[((size_t)b * SL + l) * DM + d0 + tx] = t[tx][ty + 8 * j];
  }
}

// ---------------- weight prep: fp32 -> f16 hi/lo, MFMA frag layout ----------------
// frag layout per matrix: flat f16 index f:
//   j = f&7; lane = (f>>3)&63; rest = f>>9; ks = rest & (KS16-1); nt = rest >> log2(KS16)
//   n = nt*32 + (lane&31);  k = ks*16 + ((lane>>5)&1)*8 + j
// per-layer block (81920 f16): Wq@0 Wk@16384 Wv@32768 Wo@49152 W1@65536 W2@73728 ; Wp@409600
#define PACK_TOTAL 425984
__global__ __launch_bounds__(256) void prep_weights(
    const float* __restrict__ Wq, const float* __restrict__ Wk,
    const float* __restrict__ Wv, const float* __restrict__ Wo,
    const float* __restrict__ W1, const float* __restrict__ W2,
    const float* __restrict__ Wp, f16* __restrict__ phi, f16* __restrict__ plo) {
  int idx = blockIdx.x * 256 + threadIdx.x;
  if (idx >= PACK_TOTAL) return;
  const float* src; int K, KS16, lsh; int f; bool transp = false;
  if (idx >= 409600) { f = idx - 409600; src = Wp; K = 128; KS16 = 8; lsh = 3; transp = true; }
  else {
    int layer = idx / 81920; int r = idx - layer * 81920;
    if      (r < 16384) { src = Wq + layer * 16384; f = r;         K = 128; KS16 = 8; lsh = 3; }
    else if (r < 32768) { src = Wk + layer * 16384; f = r - 16384; K = 128; KS16 = 8; lsh = 3; }
    else if (r < 49152) { src = Wv + layer * 16384; f = r - 32768; K = 128; KS16 = 8; lsh = 3; }
    else if (r < 65536) { src = Wo + layer * 16384; f = r - 49152; K = 128; KS16 = 8; lsh = 3; }
    else if (r < 73728) { src = W1 + layer * 8192;  f = r - 65536; K = 128; KS16 = 8; lsh = 3; }
    else                { src = W2 + layer * 8192;  f = r - 73728; K = 64;  KS16 = 4; lsh = 2; }
  }
  int j = f & 7, lane = (f >> 3) & 63, rest = f >> 9;
  int ks = rest & (KS16 - 1), nt = rest >> lsh;
  int n = nt * 32 + (lane & 31);
  int kk = ks * 16 + ((lane >> 5) & 1) * 8 + j;
  float x = transp ? src[(size_t)kk * 128 + n] : src[(size_t)n * K + kk];
  f16 h = (f16)x;
  phi[idx] = h;
  plo[idx] = (f16)(x - (float)h);
}

// ---------------- split-fp16 MFMA GEMM, fused epilogues ----------------
// C[64 x N] = A[64 x K] * W^T, 3-pass (hi*hi + lo*hi + hi*lo), fp32 accum.
// block: 256 thr, 4 waves; wave (mg,ng) covers rows mg*32..+31, cols ng*NGW*32..
// SRC: 0=row-major K-stride (h or y), 1=ctx gather, 3=h + final-LN
// EPI: 0=qkv scatter (3 mats), 1=residual+LN->h, 2=GELU->y, 3=final transposed store
template<int NT32, int KS16, int SRC, int EPI>
__global__ __launch_bounds__(256, 2) void gemm_fused(
    const float* __restrict__ Asrc, const f16* __restrict__ phi,
    const f16* __restrict__ plo,
    const float* __restrict__ bias0, const float* __restrict__ bias1,
    const float* __restrict__ bias2,
    float* out0, float* out1, float* out2,
    const float* __restrict__ gw, const float* __restrict__ gb,
    const float* hres) {
  constexpr int NGW = NT32 / 2;
  constexpr int K = KS16 * 16;
  __shared__ f16x8 Alds[2 * 2 * KS16 * 64];
  __shared__ f16x8 Blds[NT32 * KS16 * 64];
  __shared__ float red[64 * 4];
  int tid = threadIdx.x, lane = tid & 63, wid = tid >> 6;
  int mg = wid >> 1, ng = wid & 1;
  int row0 = blockIdx.x * 64;

  // ---- stage A (hi+lo) ----
  if constexpr (SRC == 0 || SRC == 1) {
    constexpr int OCT = 64 * (K / 8);
    for (int o = tid; o < OCT; o += 256) {
      int row = o / (K / 8);
      int k0 = (o % (K / 8)) * 8;
      float4 f0, f1;
      if constexpr (SRC == 0) {
        const float* s = Asrc + (size_t)(row0 + row) * K + k0;
        f0 = *(const float4*)(s);
        f1 = *(const float4*)(s + 4);
      } else {
        int gr = row0 + row; int bb = gr >> 12, ll = gr & (SL - 1);
        int head = k0 >> 4, e0 = k0 & 15;
        const float* s = Asrc + (((size_t)(bb * NH + head) * SL + ll) * EHD + e0);
        f0 = *(const float4*)(s);
        f1 = *(const float4*)(s + 4);
      }
      f16x8 vh, vl;
      float xs[8] = {f0.x, f0.y, f0.z, f0.w, f1.x, f1.y, f1.z, f1.w};
#pragma unroll
      for (int j = 0; j < 8; ++j) {
        f16 hh = (f16)xs[j];
        vh[j] = hh;
        vl[j] = (f16)(xs[j] - (float)hh);
      }
      int al = (row & 31) | (((k0 >> 3) & 1) << 5);
      int ks = k0 >> 4, mt = row >> 5;
      Alds[((0 * 2 + mt) * KS16 + ks) * 64 + al] = vh;
      Alds[((1 * 2 + mt) * KS16 + ks) * 64 + al] = vl;
    }
  } else {  // SRC == 3 : h rows + final LayerNorm before packing
    int row = tid >> 2, q4 = tid & 3;
    const float* s = Asrc + (size_t)(row0 + row) * 128 + q4 * 32;
    float r[32];
#pragma unroll
    for (int i = 0; i < 8; ++i) {
      float4 f = *(const float4*)(s + 4 * i);
      r[4 * i] = f.x; r[4 * i + 1] = f.y; r[4 * i + 2] = f.z; r[4 * i + 3] = f.w;
    }
    float sm = 0.f, s2 = 0.f;
#pragma unroll
    for (int i = 0; i < 32; ++i) { sm += r[i]; s2 += r[i] * r[i]; }
    sm += __shfl_xor(sm, 1, 4); sm += __shfl_xor(sm, 2, 4);
    s2 += __shfl_xor(s2, 1, 4); s2 += __shfl_xor(s2, 2, 4);
    float mean = sm * (1.f / 128.f);
    float var = s2 * (1.f / 128.f) - mean * mean;
    float rstd = 1.0f / sqrtf(var + 1e-5f);
#pragma unroll
    for (int i = 0; i < 32; ++i) {
      int kk = q4 * 32 + i;
      r[i] = (r[i] - mean) * rstd * gw[kk] + gb[kk];
    }
#pragma unroll
    for (int i = 0; i < 4; ++i) {
      int k0 = q4 * 32 + i * 8;
      f16x8 vh, vl;
#pragma unroll
      for (int j = 0; j < 8; ++j) {
        float x = r[8 * i + j];
        f16 hh = (f16)x;
        vh[j] = hh;
        vl[j] = (f16)(x - (float)hh);
      }
      int al = (row & 31) | (((k0 >> 3) & 1) << 5);
      int ks = k0 >> 4, mt = row >> 5;
      Alds[((0 * 2 + mt) * KS16 + ks) * 64 + al] = vh;
      Alds[((1 * 2 + mt) * KS16 + ks) * 64 + al] = vl;
    }
  }

  constexpr int NMAT = (EPI == 0) ? 3 : 1;
  constexpr int BCNT = NT32 * KS16 * 64;  // f16x8 (=float4) count

#define STAGE_B(SRCPTR)                                        \
  {                                                            \
    const float4* bsrc = (const float4*)(SRCPTR);              \
    float4* bdst = (float4*)Blds;                              \
    _Pragma("unroll")                                          \
    for (int i = 0; i < BCNT / 256; ++i) bdst[tid + i * 256] = bsrc[tid + i * 256]; \
  }

#define GEMM_PASS(ASEL)                                                         \
  _Pragma("unroll")                                                             \
  for (int ks = 0; ks < KS16; ++ks) {                                           \
    f16x8 afr = Alds[(((ASEL) * 2 + mg) * KS16 + ks) * 64 + lane];              \
    _Pragma("unroll")                                                           \
    for (int g = 0; g < NGW; ++g) {                                             \
      f16x8 bfr = Blds[((ng * NGW + g) * KS16 + ks) * 64 + lane];               \
      acc[g] = __builtin_amdgcn_mfma_f32_32x32x16_f16(afr, bfr, acc[g], 0, 0, 0); \
    }                                                                           \
  }

  for (int m = 0; m < NMAT; ++m) {
    if (m) __syncthreads();
    STAGE_B(phi + m * 16384)
    __syncthreads();
    f32x16 acc[NGW];
#pragma unroll
    for (int g = 0; g < NGW; ++g)
#pragma unroll
      for (int j = 0; j < 16; ++j) acc[g][j] = 0.f;
    GEMM_PASS(0)
    GEMM_PASS(1)
    __syncthreads();
    STAGE_B(plo + m * 16384)
    __syncthreads();
    GEMM_PASS(0)

    // ---- epilogue ----
    int hi4 = 4 * (lane >> 5);
    if constexpr (EPI == 0) {
      const float* bm = (m == 0) ? bias0 : (m == 1) ? bias1 : bias2;
      float* om = (m == 0) ? out0 : (m == 1) ? out1 : out2;
#pragma unroll
      for (int g = 0; g < NGW; ++g) {
        int col = ng * (NGW * 32) + g * 32 + (lane & 31);
        float bv = bm[col];
        int head = col >> 4, e = col & 15;
#pragma unroll
        for (int reg = 0; reg < 16; ++reg) {
          int row_l = (reg & 3) + 8 * (reg >> 2) + hi4;
          int grow = row0 + mg * 32 + row_l;
          int bb = grow >> 12, ll = grow & (SL - 1);
          om[((size_t)(bb * NH + head) * SL + ll) * EHD + e] = acc[g][reg] + bv;
        }
      }
    } else if constexpr (EPI == 2) {
#pragma unroll
      for (int g = 0; g < NGW; ++g) {
        int col = ng * (NGW * 32) + g * 32 + (lane & 31);
        float bv = bias0[col];
#pragma unroll
        for (int reg = 0; reg < 16; ++reg) {
          int row_l = (reg & 3) + 8 * (reg >> 2) + hi4;
          int grow = row0 + mg * 32 + row_l;
          float a = acc[g][reg] + bv;
          out0[(size_t)grow * DFF + col] = 0.5f * a * (1.f + erff(a * 0.707106781186547524f));
        }
      }
    } else if constexpr (EPI == 3) {
#pragma unroll
      for (int g = 0; g < NGW; ++g) {
        int col = ng * (NGW * 32) + g * 32 + (lane & 31);
        float bv = bias0[col];
#pragma unroll
        for (int reg = 0; reg < 16; ++reg) {
          int row_l = (reg & 3) + 8 * (reg >> 2) + hi4;
          int grow = row0 + mg * 32 + row_l;
          int bb = grow >> 12, ll = grow & (SL - 1);
          out0[((size_t)(bb * NREP + col)) * SL + ll] = acc[g][reg] + bv;
        }
      }
    } else {  // EPI == 1: residual + LayerNorm -> h
      float bv[2], gwv[2], gbv[2];
#pragma unroll
      for (int g = 0; g < NGW; ++g) {
        int col = ng * (NGW * 32) + g * 32 + (lane & 31);
        bv[g] = bias0[col]; gwv[g] = gw[col]; gbv[g] = gb[col];
      }
      float ps[16], pq[16];
#pragma unroll
      for (int reg = 0; reg < 16; ++reg) {
        int row_l = (reg & 3) + 8 * (reg >> 2) + hi4;
        int grow = row0 + mg * 32 + row_l;
        float vsum = 0.f, qsum = 0.f;
#pragma unroll
        for (int g = 0; g < NGW; ++g) {
          int col = ng * (NGW * 32) + g * 32 + (lane & 31);
          float t = acc[g][reg] + bv[g] + hres[(size_t)grow * DM + col];
          acc[g][reg] = t;
          vsum += t; qsum += t * t;
        }
        vsum += __shfl_xor(vsum, 1, 32); qsum += __shfl_xor(qsum, 1, 32);
        vsum += __shfl_xor(vsum, 2, 32); qsum += __shfl_xor(qsum, 2, 32);
        vsum += __shfl_xor(vsum, 4, 32); qsum += __shfl_xor(qsum, 4, 32);
        vsum += __shfl_xor(vsum, 8, 32); qsum += __shfl_xor(qsum, 8, 32);
        vsum += __shfl_xor(vsum, 16, 32); qsum += __shfl_xor(qsum, 16, 32);
        ps[reg] = vsum; pq[reg] = qsum;
      }
      __syncthreads();
      if ((lane & 31) == 0) {
#pragma unroll
        for (int reg = 0; reg < 16; ++reg) {
          int row_l = (reg & 3) + 8 * (reg >> 2) + hi4;
          int rl = mg * 32 + row_l;
          red[rl * 4 + ng * 2 + 0] = ps[reg];
          red[rl * 4 + ng * 2 + 1] = pq[reg];
        }
      }
      __syncthreads();
#pragma unroll
      for (int reg = 0; reg < 16; ++reg) {
        int row_l = (reg & 3) + 8 * (reg >> 2) + hi4;
        int rl = mg * 32 + row_l;
        int grow = row0 + rl;
        float st = red[rl * 4 + 0] + red[rl * 4 + 2];
        float qt = red[rl * 4 + 1] + red[rl * 4 + 3];
        float mean = st * (1.f / 128.f);
        float var = qt * (1.f / 128.f) - mean * mean;
        float rstd = 1.0f / sqrtf(var + 1e-5f);
#pragma unroll
        for (int g = 0; g < NGW; ++g) {
          int col = ng * (NGW * 32) + g * 32 + (lane & 31);
          out0[(size_t)grow * DM + col] = (acc[g][reg] - mean) * rstd * gwv[g] + gbv[g];
        }
      }
    }
  }
#undef STAGE_B
#undef GEMM_PASS
}

// ---------------- sampled scores -> M ----------------
__global__ __launch_bounds__(256) void sampM_kernel(const float* __restrict__ q,
    const float* __restrict__ k, const uint32_t* __restrict__ bits,
    float* __restrict__ M) {
  int tid = threadIdx.x;
  int bh = blockIdx.x & 63;
  int chunk = blockIdx.x >> 6;
  int l = chunk * 256 + tid;
  const float* qr = q + ((size_t)bh * SL + l) * EHD;
  float4 q0 = *(const float4*)(qr + 0);
  float4 q1 = *(const float4*)(qr + 4);
  float4 q2 = *(const float4*)(qr + 8);
  float4 q3 = *(const float4*)(qr + 12);
  const uint32_t* bl = bits + (size_t)l * NC;
  float mx = -INFINITY, sm = 0.f;
  for (int u = 0; u < NC; ++u) {
    int ki = (int)(bl[u] & (SL - 1));
    const float* kr = k + ((size_t)bh * SL + ki) * EHD;
    float4 k0 = *(const float4*)(kr + 0);
    float4 k1 = *(const float4*)(kr + 4);
    float4 k2 = *(const float4*)(kr + 8);
    float4 k3 = *(const float4*)(kr + 12);
    float s = q0.x*k0.x + q0.y*k0.y + q0.z*k0.z + q0.w*k0.w
            + q1.x*k1.x + q1.y*k1.y + q1.z*k1.z + q1.w*k1.w
            + q2.x*k2.x + q2.y*k2.y + q2.z*k2.z + q2.w*k2.w
            + q3.x*k3.x + q3.y*k3.y + q3.z*k3.z + q3.w*k3.w;
    mx = fmaxf(mx, s);
    sm += s;
  }
  M[(size_t)bh * SL + l] = mx - sm * (1.0f / (float)SL);
}

// ---------------- top-k (iterative argmax, stable ties) ----------------
__global__ void topk_kernel(const float* __restrict__ M, int* __restrict__ top) {
  int bh  = blockIdx.x;
  int tid = threadIdx.x;
  __shared__ float vals[SL];
  __shared__ float rmax[256];
  __shared__ int   ridx[256];
  for (int i = tid; i < SL; i += 256) vals[i] = M[(size_t)bh * SL + i];
  __syncthreads();
  for (int u = 0; u < NC; ++u) {
    float bm = -INFINITY; int bi = SL;
    for (int i = tid; i < SL; i += 256) {
      float vv = vals[i];
      if (vv > bm) { bm = vv; bi = i; }
    }
    rmax[tid] = bm; ridx[tid] = bi;
    __syncthreads();
    for (int s = 128; s > 0; s >>= 1) {
      if (tid < s) {
        float v2 = rmax[tid + s]; int i2 = ridx[tid + s];
        if (v2 > rmax[tid] || (v2 == rmax[tid] && i2 < ridx[tid])) {
          rmax[tid] = v2; ridx[tid] = i2;
        }
      }
      __syncthreads();
    }
    if (tid == 0) { top[bh * NC + u] = ridx[0]; vals[ridx[0]] = -INFINITY; }
    __syncthreads();
  }
}

// ---------------- V mean over L ----------------
__global__ void vmean_kernel(const float* __restrict__ v, float* __restrict__ vmean) {
  int bh  = blockIdx.x;
  int tid = threadIdx.x;
  int e = tid & 15, g = tid >> 4;
  float s = 0.f;
  for (int l = g; l < SL; l += 16) s += v[((size_t)bh * SL + l) * EHD + e];
  __shared__ float red[256];
  red[tid] = s; __syncthreads();
  for (int st = 128; st >= 16; st >>= 1) {
    if (tid < st) red[tid] += red[tid + st];
    __syncthreads();
  }
  if (tid < EHD) vmean[bh * EHD + tid] = red[tid] * (1.0f / (float)SL);
}

// ---------------- ctx = broadcast vmean (float4) ----------------
__global__ void fillctx_kernel(const float* __restrict__ vmean, float* __restrict__ ctx) {
  int t = blockIdx.x * blockDim.x + threadIdx.x;
  if (t >= NBH * SL * 4) return;
  int e0 = (t & 3) * 4;
  int bh = t >> 14;
  *(float4*)(ctx + (size_t)t * 4) = *(const float4*)(vmean + bh * EHD + e0);
}

// ---------------- flash-style attention for top-27 queries ----------------
// grid 256: blockIdx & 63 = bh (XCD-local K/V), >>6 = query group (7,7,7,6)
// wave w handles u = ug*7 + w and ug*7 + w + 4 (lane-local online softmax)
__global__ __launch_bounds__(256) void attn_flash(const float* __restrict__ q,
    const float* __restrict__ k, const float* __restrict__ v,
    const int* __restrict__ top, float* __restrict__ ctx) {
  int bh = blockIdx.x & 63, ug = blockIdx.x >> 6;
  int tid = threadIdx.x, wid = tid >> 6, lane = tid & 63;
  int base = ug * 7;
  int nq = (ug < 3) ? 7 : 6;
  bool has0 = (wid < nq);
  bool has1 = (wid + 4 < nq);
  int u0 = base + (has0 ? wid : 0);
  int u1 = base + (has1 ? wid + 4 : 0);
  int qi0 = top[bh * NC + u0];
  int qi1 = top[bh * NC + u1];
  float q0[16], q1[16];
  {
    const float* p0 = q + ((size_t)bh * SL + qi0) * EHD;
    const float* p1 = q + ((size_t)bh * SL + qi1) * EHD;
#pragma unroll
    for (int i = 0; i < 4; ++i) {
      float4 f = *(const float4*)(p0 + 4 * i);
      q0[4*i] = f.x; q0[4*i+1] = f.y; q0[4*i+2] = f.z; q0[4*i+3] = f.w;
      float4 g = *(const float4*)(p1 + 4 * i);
      q1[4*i] = g.x; q1[4*i+1] = g.y; q1[4*i+2] = g.z; q1[4*i+3] = g.w;
    }
  }
  float m0 = -INFINITY, m1 = -INFINITY, l0 = 0.f, l1 = 0.f;
  float a0[16], a1[16];
#pragma unroll
  for (int j = 0; j < 16; ++j) { a0[j] = 0.f; a1[j] = 0.f; }
  const float* kb = k + (size_t)bh * SL * EHD;
  const float* vb = v + (size_t)bh * SL * EHD;
  for (int t = 0; t < 64; ++t) {
    int ki = lane + (t << 6);
    float kr[16], vr[16];
    {
      const float* kp = kb + (size_t)ki * EHD;
      const float* vp = vb + (size_t)ki * EHD;
#pragma unroll
      for (int i = 0; i < 4; ++i) {
        float4 f = *(const float4*)(kp + 4 * i);
        kr[4*i] = f.x; kr[4*i+1] = f.y; kr[4*i+2] = f.z; kr[4*i+3] = f.w;
        float4 g = *(const float4*)(vp + 4 * i);
        vr[4*i] = g.x; vr[4*i+1] = g.y; vr[4*i+2] = g.z; vr[4*i+3] = g.w;
      }
    }
    float s0 = 0.f, s1 = 0.f;
#pragma unroll
    for (int j = 0; j < 16; ++j) { s0 += q0[j] * kr[j]; s1 += q1[j] * kr[j]; }
    s0 *= 0.25f; s1 *= 0.25f;
    {
      float d = s0 - m0;
      float e = expf(-fabsf(d));
      bool gt = d > 0.f;
      float c = gt ? e : 1.f;
      float p = gt ? 1.f : e;
      m0 = gt ? s0 : m0;
      l0 = l0 * c + p;
#pragma unroll
      for (int j = 0; j < 16; ++j) a0[j] = a0[j] * c + p * vr[j];
    }
    {
      float d = s1 - m1;
      float e = expf(-fabsf(d));
      bool gt = d > 0.f;
      float c = gt ? e : 1.f;
      float p = gt ? 1.f : e;
      m1 = gt ? s1 : m1;
      l1 = l1 * c + p;
#pragma unroll
      for (int j = 0; j < 16; ++j) a1[j] = a1[j] * c + p * vr[j];
    }
  }
  // butterfly merge across 64 lanes
#pragma unroll
  for (int off = 1; off < 64; off <<= 1) {
    {
      float mo = __shfl_xor(m0, off, 64);
      float lo_ = __shfl_xor(l0, off, 64);
      float mn = fmaxf(m0, mo);
      float cs = expf(m0 - mn), co = expf(mo - mn);
      l0 = l0 * cs + lo_ * co;
#pragma unroll
      for (int j = 0; j < 16; ++j) {
        float ao = __shfl_xor(a0[j], off, 64);
        a0[j] = a0[j] * cs + ao * co;
      }
      m0 = mn;
    }
    {
      float mo = __shfl_xor(m1, off, 64);
      float lo_ = __shfl_xor(l1, off, 64);
      float mn = fmaxf(m1, mo);
      float cs = expf(m1 - mn), co = expf(mo - mn);
      l1 = l1 * cs + lo_ * co;
#pragma unroll
      for (int j = 0; j < 16; ++j) {
        float ao = __shfl_xor(a1[j], off, 64);
        a1[j] = a1[j] * cs + ao * co;
      }
      m1 = mn;
    }
  }
  if (lane == 0 && has0) {
    float inv = 1.0f / l0;
    float* o = ctx + ((size_t)bh * SL + qi0) * EHD;
#pragma unroll
    for (int j = 0; j < 16; ++j) o[j] = a0[j] * inv;
  }
  if (lane == 0 && has1) {
    float inv = 1.0f / l1;
    float* o = ctx + ((size_t)bh * SL + qi1) * EHD;
#pragma unroll
    for (int j = 0; j < 16; ++j) o[j] = a1[j] * inv;
  }
}

// ---------------- launch ----------------
extern "C" void kernel_launch(void* const* d_in, const int* in_sizes, int n_in,
                              void* d_out, int out_size, void* d_ws, size_t ws_size,
                              hipStream_t stream) {
  const float* x   = (const float*)d_in[0];
  const float* Wq  = (const float*)d_in[1];
  const float* bq  = (const float*)d_in[2];
  const float* Wk  = (const float*)d_in[3];
  const float* bk  = (const float*)d_in[4];
  const float* Wv  = (const float*)d_in[5];
  const float* bv  = (const float*)d_in[6];
  const float* Wo  = (const float*)d_in[7];
  const float* bo  = (const float*)d_in[8];
  const float* W1  = (const float*)d_in[9];
  const float* b1  = (const float*)d_in[10];
  const float* W2  = (const float*)d_in[11];
  const float* b2  = (const float*)d_in[12];
  const float* ln1w = (const float*)d_in[13];
  const float* ln1b = (const float*)d_in[14];
  const float* ln2w = (const float*)d_in[15];
  const float* ln2b = (const float*)d_in[16];
  const float* lnfw = (const float*)d_in[17];
  const float* lnfb = (const float*)d_in[18];
  const float* Wp  = (const float*)d_in[19];
  const float* bp  = (const float*)d_in[20];
  float* out = (float*)d_out;

  float* ws = (float*)d_ws;
  float* h     = ws;                      // 4194304
  float* q     = ws + 4194304;            // 4194304
  float* k     = ws + 8388608;            // 4194304
  float* v     = ws + 12582912;           // 4194304
  float* ctx   = ws + 16777216;           // 4194304
  float* y     = ws + 20971520;           // 2097152
  float* M     = ws + 23068672;           // 262144
  float* vmean = ws + 23330816;           // 1024
  int*   top   = (int*)(ws + 23331840);   // 2048 float slots
  uint32_t* bits = (uint32_t*)(ws + 23333888); // 110592 slots
  f16* phi = (f16*)(ws + 23444480);       // 425984 f16 = 212992 float slots
  f16* plo = (f16*)(ws + 23657472);       // 425984 f16

  transpose_x_kernel<<<dim3(SL / 32, DM / 32, NB), 256, 0, stream>>>(x, h);
  prep_weights<<<(PACK_TOTAL + 255) / 256, 256, 0, stream>>>(
      Wq, Wk, Wv, Wo, W1, W2, Wp, phi, plo);

  for (int l = 0; l < NLAY; ++l) {
    size_t lb = (size_t)l * 81920;
    gen_bits_kernel<<<(SL * NC + 255) / 256, 256, 0, stream>>>(bits, l);
    gemm_fused<4, 8, 0, 0><<<NROWS / 64, 256, 0, stream>>>(
        h, phi + lb, plo + lb, bq + l * DM, bk + l * DM, bv + l * DM,
        q, k, v, nullptr, nullptr, nullptr);
    sampM_kernel<<<NBH * SL / 256, 256, 0, stream>>>(q, k, bits, M);
    topk_kernel<<<NBH, 256, 0, stream>>>(M, top);
    vmean_kernel<<<NBH, 256, 0, stream>>>(v, vmean);
    fillctx_kernel<<<(NBH * SL * 4 + 255) / 256, 256, 0, stream>>>(vmean, ctx);
    attn_flash<<<256, 256, 0, stream>>>(q, k, v, top, ctx);
    gemm_fused<4, 8, 1, 1><<<NROWS / 64, 256, 0, stream>>>(
        ctx, phi + lb + 49152, plo + lb + 49152, bo + l * DM, nullptr, nullptr,
        h, nullptr, nullptr, ln1w + l * DM, ln1b + l * DM, h);
    gemm_fused<2, 8, 0, 2><<<NROWS / 64, 256, 0, stream>>>(
        h, phi + lb + 65536, plo + lb + 65536, b1 + l * DFF, nullptr, nullptr,
        y, nullptr, nullptr, nullptr, nullptr, nullptr);
    gemm_fused<4, 4, 0, 1><<<NROWS / 64, 256, 0, stream>>>(
        y, phi + lb + 73728, plo + lb + 73728, b2 + l * DM, nullptr, nullptr,
        h, nullptr, nullptr, ln2w + l * DM, ln2b + l * DM, h);
  }

  gemm_fused<4, 8, 3, 3><<<NROWS / 64, 256, 0, stream>>>(
      h, phi + 409600, plo + 409600, bp, nullptr, nullptr,
      out, nullptr, nullptr, lnfw, lnfb, nullptr);
}